// Round 2
// baseline (332.448 us; speedup 1.0000x reference)
//
#include <hip/hip_runtime.h>

#define DIM 256
#define NC 16
#define NG 1000
#define EBLOCKS 512
#define ETHREADS 512

// ---------------------------------------------------------------------------
// Phase 1: hidden[n][c] = dot(x[n], W[:,c]) + b[c]
// Thread (n, h): partial dot over dims [h*128, h*128+128) for ALL 16 classes,
// then pairwise __shfl_xor(1) butterfly. x bytes disjoint per thread -> x is
// read exactly once (102.4 MB, the floor).
// ---------------------------------------------------------------------------
__global__ void hidden_kernel(const float* __restrict__ x,
                              const float* __restrict__ W,
                              const float* __restrict__ b,
                              float* __restrict__ hidden, int N) {
    __shared__ float Ws[DIM * NC];
    for (int i = threadIdx.x; i < DIM * NC; i += blockDim.x) Ws[i] = W[i];
    __syncthreads();

    int gid = blockIdx.x * blockDim.x + threadIdx.x;
    int n = gid >> 1;
    if (n >= N) return;
    int h = gid & 1;

    float acc[NC];
#pragma unroll
    for (int c = 0; c < NC; ++c) acc[c] = (h == 0) ? b[c] : 0.f;

    const float4* x4 = (const float4*)(x + (size_t)n * DIM + h * 128);
    const float* Wh = Ws + (h * 128) * NC;
#pragma unroll 4
    for (int d4 = 0; d4 < 32; ++d4) {
        float4 xv = x4[d4];
        const float xs[4] = {xv.x, xv.y, xv.z, xv.w};
#pragma unroll
        for (int jj = 0; jj < 4; ++jj) {
            const float* wrow = Wh + (d4 * 4 + jj) * NC;
#pragma unroll
            for (int c = 0; c < NC; ++c)
                acc[c] = fmaf(xs[jj], wrow[c], acc[c]);
        }
    }

    // pair reduction: after this, both lanes hold the full 16 sums
#pragma unroll
    for (int c = 0; c < NC; ++c) acc[c] += __shfl_xor(acc[c], 1);

    // lane h stores classes [h*8, h*8+8)
    int c0 = h * 8;
    float4* out4 = (float4*)(hidden + (size_t)n * NC + c0);
    out4[0] = make_float4(acc[c0 + 0], acc[c0 + 1], acc[c0 + 2], acc[c0 + 3]);
    out4[1] = make_float4(acc[c0 + 4], acc[c0 + 5], acc[c0 + 6], acc[c0 + 7]);
}

// ---------------------------------------------------------------------------
// Phase 2a: node -> graph id (searchsorted right over sorted ed_idx)
// ---------------------------------------------------------------------------
__global__ void seg_kernel(const int* __restrict__ ed_idx,
                           int* __restrict__ node_seg, int N, int G) {
    int n = blockIdx.x * blockDim.x + threadIdx.x;
    if (n >= N) return;
    int lo = 0, hi = G;
    while (lo < hi) {
        int mid = (lo + hi) >> 1;
        if (ed_idx[mid] <= n) lo = mid + 1; else hi = mid;
    }
    node_seg[n] = lo;
}

// ---------------------------------------------------------------------------
// Phase 2b: fused SpMM + pooling. Item = (edge, half-row). LDS accumulator,
// per-block private partial written with plain stores (PRIV=true) or legacy
// global-atomic merge (PRIV=false fallback when ws is small).
// Manual 2x unroll: two independent gather chains in flight per thread.
// ---------------------------------------------------------------------------
template <bool PRIV>
__global__ void __launch_bounds__(ETHREADS) edge_kernel(
    const int* __restrict__ rows, const int* __restrict__ cols,
    const float* __restrict__ vals, const float* __restrict__ hidden,
    const int* __restrict__ node_seg, float* __restrict__ dst, int nE) {
    __shared__ float acc[NG * NC];  // 64000 B
    for (int i = threadIdx.x; i < NG * NC; i += blockDim.x) acc[i] = 0.f;
    __syncthreads();

    const int nItems = nE * 2;
    const int stride = gridDim.x * blockDim.x;
    const int stride2 = stride * 2;
    int tid = blockIdx.x * blockDim.x + threadIdx.x;

    for (int it = tid; it < nItems; it += stride2) {
        int itB = it + stride;
        bool okB = itB < nItems;

        int eA = it >> 1, hA = (it & 1) << 3;
        int eB = okB ? (itB >> 1) : eA;
        int hB = okB ? ((itB & 1) << 3) : hA;

        int rA = rows[eA], cA = cols[eA];
        int rB = rows[eB], cB = cols[eB];
        float vA = vals[eA];
        float vB = okB ? vals[eB] : 0.f;

        int gA = node_seg[rA];
        int gB = node_seg[rB];

        const float4* pA = (const float4*)(hidden + (size_t)cA * NC + hA);
        float4 a0 = pA[0], a1 = pA[1];
        const float4* pB = (const float4*)(hidden + (size_t)cB * NC + hB);
        float4 b0 = pB[0], b1 = pB[1];

        if (gA < NG) {
            float* p = acc + gA * NC + hA;
            atomicAdd(p + 0, vA * a0.x);
            atomicAdd(p + 1, vA * a0.y);
            atomicAdd(p + 2, vA * a0.z);
            atomicAdd(p + 3, vA * a0.w);
            atomicAdd(p + 4, vA * a1.x);
            atomicAdd(p + 5, vA * a1.y);
            atomicAdd(p + 6, vA * a1.z);
            atomicAdd(p + 7, vA * a1.w);
        }
        if (okB && gB < NG) {
            float* p = acc + gB * NC + hB;
            atomicAdd(p + 0, vB * b0.x);
            atomicAdd(p + 1, vB * b0.y);
            atomicAdd(p + 2, vB * b0.z);
            atomicAdd(p + 3, vB * b0.w);
            atomicAdd(p + 4, vB * b1.x);
            atomicAdd(p + 5, vB * b1.y);
            atomicAdd(p + 6, vB * b1.z);
            atomicAdd(p + 7, vB * b1.w);
        }
    }
    __syncthreads();

    if (PRIV) {
        float* out = dst + (size_t)blockIdx.x * (NG * NC);
        for (int i = threadIdx.x; i < NG * NC; i += blockDim.x) out[i] = acc[i];
    } else {
        for (int i = threadIdx.x; i < NG * NC; i += blockDim.x)
            atomicAdd(&dst[i], acc[i]);
    }
}

// ---------------------------------------------------------------------------
// Phase 3: fold partials[EBLOCKS][NG*NC] into out. blockIdx.y picks a chunk
// of 64 partial-blocks; 8 atomics per output address (negligible contention).
// ---------------------------------------------------------------------------
__global__ void reduce_kernel(const float* __restrict__ partials,
                              float* __restrict__ out) {
    int i = blockIdx.x * blockDim.x + threadIdx.x;
    if (i >= NG * NC) return;
    const int per = EBLOCKS / 8;  // 64
    const float* p = partials + (size_t)(blockIdx.y * per) * (NG * NC) + i;
    float s0 = 0.f, s1 = 0.f, s2 = 0.f, s3 = 0.f;
#pragma unroll 4
    for (int k = 0; k < per; k += 4) {
        s0 += p[(size_t)(k + 0) * (NG * NC)];
        s1 += p[(size_t)(k + 1) * (NG * NC)];
        s2 += p[(size_t)(k + 2) * (NG * NC)];
        s3 += p[(size_t)(k + 3) * (NG * NC)];
    }
    atomicAdd(&out[i], (s0 + s1) + (s2 + s3));
}

extern "C" void kernel_launch(void* const* d_in, const int* in_sizes, int n_in,
                              void* d_out, int out_size, void* d_ws, size_t ws_size,
                              hipStream_t stream) {
    const float* x      = (const float*)d_in[0];
    const int*   ed_idx = (const int*)  d_in[1];
    const int*   rows   = (const int*)  d_in[2];
    const int*   cols   = (const int*)  d_in[3];
    const float* vals   = (const float*)d_in[4];
    const float* W      = (const float*)d_in[5];
    const float* b      = (const float*)d_in[6];
    float* out = (float*)d_out;

    int N  = in_sizes[0] / DIM;   // 100000
    int G  = in_sizes[1];         // 1000
    int nE = in_sizes[2];         // 3200000

    size_t hidden_bytes = (size_t)N * NC * sizeof(float);        // 6.4 MB
    size_t seg_bytes    = (size_t)N * sizeof(int);               // 0.4 MB
    size_t part_bytes   = (size_t)EBLOCKS * NG * NC * sizeof(float);  // 32.768 MB

    float* hidden   = (float*)d_ws;
    int*   node_seg = (int*)((char*)d_ws + hidden_bytes);
    float* partials = (float*)((char*)d_ws + hidden_bytes + seg_bytes);

    bool priv = ws_size >= hidden_bytes + seg_bytes + part_bytes;

    hipMemsetAsync(d_out, 0, (size_t)out_size * sizeof(float), stream);

    hidden_kernel<<<(2 * N + 255) / 256, 256, 0, stream>>>(x, W, b, hidden, N);
    seg_kernel<<<(N + 255) / 256, 256, 0, stream>>>(ed_idx, node_seg, N, G);

    if (priv) {
        edge_kernel<true><<<EBLOCKS, ETHREADS, 0, stream>>>(
            rows, cols, vals, hidden, node_seg, partials, nE);
        dim3 rg((NG * NC + 255) / 256, 8);
        reduce_kernel<<<rg, 256, 0, stream>>>(partials, out);
    } else {
        edge_kernel<false><<<EBLOCKS, ETHREADS, 0, stream>>>(
            rows, cols, vals, hidden, node_seg, out, nE);
    }
}